// Round 10
// baseline (625.414 us; speedup 1.0000x reference)
//
#include <hip/hip_runtime.h>
#include <hip/hip_fp16.h>

// Problem constants (B=1, D=128, H=64, W=96, 4 levels, radius 4)
#define D 128
#define H0 64
#define W0 96
#define HW0 6144
#define INV_SQRT_D 0.08838834764831843f

// Half-precision feature-map workspace (offsets in _Float16 units)
#define H_F1T0 0
#define H_F1T1 786432
#define H_F1T2 983040
#define H_F1T3 1032192
#define H_F2T0 1048576
#define H_F2T1 1835008
#define H_F2T2 2031616
#define H_F2T3 2080768
// Coords (fp32, offsets in float units)
#define OFF_C1 2097152
#define OFF_C2 2100224
#define OFF_C3 2100992
// Barrier counter (uint32 index into ws; byte 8.8MB, beyond all data)
#define CNT_U32 2200000

// Output offsets (floats)
#define OUT_L0 0
#define OUT_L1 497664
#define OUT_L2 622080
#define OUT_L3 653184

#define NBLK 510

typedef _Float16 h2 __attribute__((ext_vector_type(2)));
union F4H { float4 f; h2 h[4]; };

__device__ __forceinline__ float dot2f(h2 a, h2 b, float c) {
#if __has_builtin(__builtin_amdgcn_fdot2)
    return __builtin_amdgcn_fdot2(a, b, c, false);
#else
    return c + (float)a.x * (float)b.x + (float)a.y * (float)b.y;
#endif
}

__device__ __forceinline__ void gp_to_level(int gp, int& level, int& p) {
    if (gp < 6144)      { level = 0; p = gp; }
    else if (gp < 7680) { level = 1; p = gp - 6144; }
    else if (gp < 8064) { level = 2; p = gp - 7680; }
    else                { level = 3; p = gp - 8064; }
}

// ---------------------------------------------------------------------------
// Single fused kernel: 510 blocks x 1024 threads, 2 blocks/CU (co-resident
// by the 2048-thr/CU cap; launch_bounds(1024,8) pins VGPR<=64 so residency
// is guaranteed). Phase A: wave-local prep jobs. Hand-rolled agent-scope
// grid barrier (r7's grid.sync proved the fence mechanics). Phase B: dots.
// Phase C: combine.
// ---------------------------------------------------------------------------
__global__ __launch_bounds__(1024, 8) void k_all(const float* __restrict__ f1,
                                                 const float* __restrict__ f2,
                                                 const float* __restrict__ coords,
                                                 float* __restrict__ ws,
                                                 float* __restrict__ out) {
    __shared__ float smem[8 * 1088];   // A: 8 prep waves * (64px*17) ; C: Gs+cxy
    _Float16* wh = (_Float16*)ws;
    const _Float16* whc = (const _Float16*)ws;

    const int b = blockIdx.x;
    const int t = threadIdx.x;
    const int w = t >> 6;
    const int ln = t & 63;

    // ================= Phase A: prep (wave-local jobs) =================
    if (b < 192 && w < 8) {
        // tile-slab job: 96 tiles x 2 maps x 8 d-slabs(16d) = 1536 wave-jobs
        const int job = b * 8 + w;
        const int m = job / 768;
        const int rem = job - m * 768;
        const int tile = rem >> 3;
        const int slab = rem & 7;
        const int tr = tile / 12, tc = tile - (tile / 12) * 12;
        const float* in = (m ? f2 : f1) + slab * 16 * HW0;
        float* T = smem + w * 1088;    // [px][dd] stride 17

        const int gbase = (tr * 8 + (ln >> 3)) * W0 + tc * 8 + (ln & 7);
#pragma unroll
        for (int dd = 0; dd < 16; ++dd)
            T[ln * 17 + dd] = in[dd * HW0 + gbase];
        // wave-coherent LDS: compiler inserts lgkmcnt waits before reads

        // transposed L0 (fp16): 64 px rows of 16 contiguous halves (32B)
        _Float16* o0 = wh + (m ? H_F2T0 : H_F1T0) + slab * 16;
        const int ddl = ln & 15;
#pragma unroll
        for (int pass = 0; pass < 16; ++pass) {
            int pl = pass * 4 + (ln >> 4);
            int gp = (tr * 8 + (pl >> 3)) * W0 + tc * 8 + (pl & 7);
            o0[gp * D + ddl] = (_Float16)T[pl * 17 + ddl];
        }
        // L1 pool: 16 px x 16 dd
        _Float16* o1 = wh + (m ? H_F2T1 : H_F1T1) + slab * 16;
#pragma unroll
        for (int pass = 0; pass < 4; ++pass) {
            int p1 = pass * 4 + (ln >> 4);
            int i1 = p1 >> 2, j1 = p1 & 3;
            int l00 = (i1 * 2) * 8 + j1 * 2;
            float v = T[l00 * 17 + ddl] + T[(l00 + 1) * 17 + ddl]
                    + T[(l00 + 8) * 17 + ddl] + T[(l00 + 9) * 17 + ddl];
            o1[((tr * 4 + i1) * 48 + tc * 4 + j1) * D + ddl] = (_Float16)(0.25f * v);
        }
        // L2 pool: 4 px x 16 dd
        _Float16* o2 = wh + (m ? H_F2T2 : H_F1T2) + slab * 16;
        {
            int p2 = ln >> 4;
            int i2 = p2 >> 1, j2 = p2 & 1;
            float acc = 0.0f;
#pragma unroll
            for (int a = 0; a < 4; ++a)
#pragma unroll
                for (int c2 = 0; c2 < 4; ++c2)
                    acc += T[((i2 * 4 + a) * 8 + j2 * 4 + c2) * 17 + ddl];
            o2[((tr * 2 + i2) * 24 + tc * 2 + j2) * D + ddl] = (_Float16)(acc * 0.0625f);
        }
        // L3 pool: 1 px x 16 dd (quarter-sums + 2 shfl)
        _Float16* o3 = wh + (m ? H_F2T3 : H_F1T3) + slab * 16;
        {
            int q = ln >> 4;
            float acc = 0.0f;
#pragma unroll
            for (int l2 = 0; l2 < 16; ++l2)
                acc += T[(q * 16 + l2) * 17 + ddl];
            acc += __shfl_xor(acc, 16);
            acc += __shfl_xor(acc, 32);
            if (ln < 16) o3[(tr * 12 + tc) * D + ln] = (_Float16)(acc * 0.015625f);
        }
    } else if (b < 8 && w >= 8) {
        // coords resize (jax.image.resize linear, antialias=True) + /2^l
        int idx = b * 512 + (t - 512);
        if (idx < 4032) {
            int level, r = idx;
            if (r < 3072) { level = 1; }
            else if (r < 3840) { level = 2; r -= 3072; }
            else { level = 3; r -= 3840; }
            const int Hl = H0 >> level, Wl = W0 >> level;
            const float ff = (float)(1 << level);
            const int npix = Hl * Wl;
            const int ch = r / npix;
            const int rem = r - ch * npix;
            const int ho = rem / Wl, wo = rem - (rem / Wl) * Wl;

            const float sfy = (ho + 0.5f) * ff - 0.5f;
            const float sfx = (wo + 0.5f) * ff - 0.5f;
            int ylo = max(0, (int)ceilf(sfy - ff));
            int yhi = min(H0 - 1, (int)floorf(sfy + ff));
            int xlo = max(0, (int)ceilf(sfx - ff));
            int xhi = min(W0 - 1, (int)floorf(sfx + ff));

            float acc = 0.0f, wsum_y = 0.0f, wsum_x = 0.0f;
            for (int iy = ylo; iy <= yhi; ++iy) {
                float wy = fmaxf(1.0f - fabsf(sfy - (float)iy) / ff, 0.0f);
                wsum_y += wy;
                float rowacc = 0.0f;
                for (int ix = xlo; ix <= xhi; ++ix) {
                    float wx = fmaxf(1.0f - fabsf(sfx - (float)ix) / ff, 0.0f);
                    if (iy == ylo) wsum_x += wx;
                    rowacc += wx * coords[ch * HW0 + iy * W0 + ix];
                }
                acc += wy * rowacc;
            }
            float val = acc / (wsum_y * wsum_x) / ff;
            const int coffs[4] = {0, OFF_C1, OFF_C2, OFF_C3};
            ws[coffs[level] + ch * npix + ho * Wl + wo] = val;
        }
    }

    // ================= grid barrier (all 510 blocks co-resident) =========
    __syncthreads();
    {
        unsigned* cnt = (unsigned*)ws + CNT_U32;
        if (t == 0) {
            __threadfence();   // agent release: make prep writes visible
            __hip_atomic_fetch_add(cnt, 1u, __ATOMIC_ACQ_REL,
                                   __HIP_MEMORY_SCOPE_AGENT);
            unsigned v;
            do {
                __builtin_amdgcn_s_sleep(8);
                v = __hip_atomic_load(cnt, __ATOMIC_ACQUIRE,
                                      __HIP_MEMORY_SCOPE_AGENT);
                // ws is poisoned to 0xAA (or zeroed) before each launch:
                // done when v == init + NBLK for init in {0, 0xAAAAAAAA}
            } while ((v - (unsigned)NBLK) != 0u &&
                     (v - (unsigned)NBLK) != 0xAAAAAAAAu);
        }
    }
    __syncthreads();
    __threadfence();           // acquire for all waves (L1 invalidate)

    // ================= Phase B: grid dots (one wave per pixel) ===========
    __shared__ float GsBase[1];  // (alias helper; real alias below)
    float* Gs  = smem;           // 16*101
    float* cxs = smem + 1616;    // 16
    float* cys = smem + 1632;    // 16

    const int gp = b * 16 + w;
    int level, p;
    gp_to_level(gp, level, p);
    const int Hl = H0 >> level, Wl = W0 >> level;
    const int npix = Hl * Wl;

    const int f1offs[4] = {H_F1T0, H_F1T1, H_F1T2, H_F1T3};
    const int f2offs[4] = {H_F2T0, H_F2T1, H_F2T2, H_F2T3};
    const int coffs[4]  = {0, OFF_C1, OFF_C2, OFF_C3};
    const int outoffs[4] = {OUT_L0, OUT_L1, OUT_L2, OUT_L3};

    const _Float16* f2t = whc + f2offs[level];
    const float* cp = (level == 0) ? coords : (ws + coffs[level]);

    const int oct = ln >> 3;
    const int sub = ln & 7;

    const _Float16* f1p = whc + f1offs[level] + p * D + sub * 8;
    F4H a0, a1;
    a0.f = *(const float4*)(f1p);
    a1.f = *(const float4*)(f1p + 64);

    const float cx = cp[p];
    const float cy = cp[npix + p];
    if (ln == 0) { cxs[w] = cx; cys[w] = cy; }
    const int fx = (int)floorf(cx), fy = (int)floorf(cy);

    int qoff[13];
#pragma unroll
    for (int i = 0; i < 13; ++i) {
        int gc = min(i * 8 + oct, 99);
        int gy = gc / 10;
        int gx = gc - gy * 10;
        int iy = min(max(fy - 4 + gy, 0), Hl - 1);
        int ix = min(max(fx - 4 + gx, 0), Wl - 1);
        qoff[i] = (iy * Wl + ix) * D + sub * 8;
    }

#pragma unroll
    for (int i = 0; i < 13; ++i) {
        const _Float16* row = f2t + qoff[i];
        F4H v0, v1;
        v0.f = *(const float4*)(row);
        v1.f = *(const float4*)(row + 64);
        float s = 0.0f;
        s = dot2f(a0.h[0], v0.h[0], s);
        s = dot2f(a0.h[1], v0.h[1], s);
        s = dot2f(a0.h[2], v0.h[2], s);
        s = dot2f(a0.h[3], v0.h[3], s);
        s = dot2f(a1.h[0], v1.h[0], s);
        s = dot2f(a1.h[1], v1.h[1], s);
        s = dot2f(a1.h[2], v1.h[2], s);
        s = dot2f(a1.h[3], v1.h[3], s);
        s += __shfl_xor(s, 1);
        s += __shfl_xor(s, 2);
        s += __shfl_xor(s, 4);
        int g = i * 8 + oct;
        if (sub == 0 && g < 100) Gs[w * 101 + g] = s;
    }
    __syncthreads();

    // ================= Phase C: combine (block = 16 consecutive pixels) ==
    {
        const int px = t & 15;
        const int kk = t >> 4;          // 0..63
        int lv0, p0;
        gp_to_level(b * 16, lv0, p0);
        const int Hb = H0 >> lv0, Wb = W0 >> lv0;
        const int npb = Hb * Wb;
        float* outp = out + outoffs[lv0] + p0 + px;
        const float bx = cxs[px], by = cys[px];
        const float Wm1 = (float)(Wb - 1), Hm1 = (float)(Hb - 1);
        const float* Gp = &Gs[px * 101];

        for (int k = kk; k < 81; k += 64) {
            int dxi = k / 9, dyi = k - (k / 9) * 9;
            float x = fminf(fmaxf(bx + (float)(dxi - 4), 0.0f), Wm1);
            float y = fminf(fmaxf(by + (float)(dyi - 4), 0.0f), Hm1);
            float wx1 = x - floorf(x), wx0 = 1.0f - wx1;
            float wy1 = y - floorf(y), wy0 = 1.0f - wy1;
            int g00 = dyi * 10 + dxi;
            float v = wx0 * wy0 * Gp[g00]      + wx1 * wy0 * Gp[g00 + 1]
                    + wx0 * wy1 * Gp[g00 + 10] + wx1 * wy1 * Gp[g00 + 11];
            outp[k * npb] = v * INV_SQRT_D;
        }
    }
}

// ---------------------------------------------------------------------------
extern "C" void kernel_launch(void* const* d_in, const int* in_sizes, int n_in,
                              void* d_out, int out_size, void* d_ws, size_t ws_size,
                              hipStream_t stream) {
    const float* fmap1  = (const float*)d_in[0];
    const float* fmap2  = (const float*)d_in[1];
    const float* coords = (const float*)d_in[2];
    float* out = (float*)d_out;
    float* ws = (float*)d_ws;

    k_all<<<dim3(NBLK), dim3(1024), 0, stream>>>(fmap1, fmap2, coords, ws, out);
}

// Round 11
// 78.617 us; speedup vs baseline: 7.9552x; 7.9552x over previous
//
#include <hip/hip_runtime.h>
#include <hip/hip_fp16.h>

// Problem constants (B=1, D=128, H=64, W=96, 4 levels, radius 4)
#define D 128
#define H0 64
#define W0 96
#define HW0 6144
#define INV_SQRT_D 0.08838834764831843f

// Half-precision feature-map workspace (offsets in _Float16 units)
#define H_F1T0 0
#define H_F1T1 786432
#define H_F1T2 983040
#define H_F1T3 1032192
#define H_F2T0 1048576
#define H_F2T1 1835008
#define H_F2T2 2031616
#define H_F2T3 2080768

// Output offsets (floats)
#define OUT_L0 0
#define OUT_L1 497664
#define OUT_L2 622080
#define OUT_L3 653184

typedef _Float16 h2 __attribute__((ext_vector_type(2)));
union F4H { float4 f; h2 h[4]; };

__device__ __forceinline__ float dot2f(h2 a, h2 b, float c) {
#if __has_builtin(__builtin_amdgcn_fdot2)
    return __builtin_amdgcn_fdot2(a, b, c, false);
#else
    return c + (float)a.x * (float)b.x + (float)a.y * (float)b.y;
#endif
}

__device__ __forceinline__ void gp_to_level(int gp, int& level, int& p) {
    if (gp < 6144)      { level = 0; p = gp; }
    else if (gp < 7680) { level = 1; p = gp - 6144; }
    else if (gp < 8064) { level = 2; p = gp - 7680; }
    else                { level = 3; p = gp - 8064; }
}

// ---------------------------------------------------------------------------
// K1: tile transpose + all pool levels, fp16 outputs. 384 blocks (96 tiles x
// 2 maps x 2 d-halves). No coords work (moved into k_dc).
// ---------------------------------------------------------------------------
__global__ __launch_bounds__(256) void k_prep(const float* __restrict__ f1,
                                              const float* __restrict__ f2,
                                              float* __restrict__ ws) {
    const int b = blockIdx.x;
    const int t = threadIdx.x;
    _Float16* wh = (_Float16*)ws;
    __shared__ float T[64 * 69];    // [pixel_local][d_local], stride 69
    const int m = b / 192;
    const int rb = b - m * 192;
    const int tix = rb >> 1;        // 0..95
    const int dh = rb & 1;          // d half
    const int tr = tix / 12, tc = tix - (tix / 12) * 12;
    const float* in = (m ? f2 : f1) + dh * 64 * HW0;

    const int l = t & 63;
    const int gbase = (tr * 8 + (l >> 3)) * W0 + tc * 8 + (l & 7);
#pragma unroll 4
    for (int pass = 0; pass < 16; ++pass) {
        int d = pass * 4 + (t >> 6);
        T[l * 69 + d] = in[d * HW0 + gbase];
    }
    __syncthreads();

    _Float16* o0 = wh + (m ? H_F2T0 : H_F1T0) + dh * 64;
#pragma unroll 4
    for (int pass = 0; pass < 16; ++pass) {
        int e = t + pass * 256;
        int pl = e >> 6, c = e & 63;
        int gp = (tr * 8 + (pl >> 3)) * W0 + tc * 8 + (pl & 7);
        o0[gp * D + c] = (_Float16)T[pl * 69 + c];
    }
    _Float16* o1 = wh + (m ? H_F2T1 : H_F1T1) + dh * 64;
#pragma unroll
    for (int pass = 0; pass < 4; ++pass) {
        int e = t + pass * 256;
        int d = e & 63, p1 = e >> 6;            // p1 0..15
        int i1 = p1 >> 2, j1 = p1 & 3;
        int l00 = (i1 * 2) * 8 + j1 * 2;
        float v = T[l00 * 69 + d] + T[(l00 + 1) * 69 + d]
                + T[(l00 + 8) * 69 + d] + T[(l00 + 9) * 69 + d];
        o1[((tr * 4 + i1) * 48 + tc * 4 + j1) * D + d] = (_Float16)(0.25f * v);
    }
    _Float16* o2 = wh + (m ? H_F2T2 : H_F1T2) + dh * 64;
    {
        int d = t & 63, p2 = t >> 6;            // p2 0..3
        int i2 = p2 >> 1, j2 = p2 & 1;
        float acc = 0.0f;
#pragma unroll
        for (int a = 0; a < 4; ++a)
#pragma unroll
            for (int c2 = 0; c2 < 4; ++c2)
                acc += T[((i2 * 4 + a) * 8 + j2 * 4 + c2) * 69 + d];
        o2[((tr * 2 + i2) * 24 + tc * 2 + j2) * D + d] = (_Float16)(acc * 0.0625f);
    }
    _Float16* o3 = wh + (m ? H_F2T3 : H_F1T3) + dh * 64;
    if (t < 64) {
        float acc = 0.0f;
        for (int l2 = 0; l2 < 64; ++l2) acc += T[l2 * 69 + t];
        o3[(tr * 12 + tc) * D + t] = (_Float16)(acc * 0.015625f);
    }
}

// ---------------------------------------------------------------------------
// K2: fused coords+dots+combine. Block = 1024 thr = 16 waves = 16
// consecutive pixels (level-uniform blocks). For level>=1, each wave
// computes its pixel's resized coords wave-parallel (<=289 taps over 64
// lanes + butterfly reduce; flat-sum normalization == separable per-axis
// normalization). Dots: 8-lane interleaved fp16 slices, 3-shfl reduce,
// G->LDS. Combine: coalesced 64B-line stores.
// ---------------------------------------------------------------------------
__global__ __launch_bounds__(1024) void k_dc(const float* __restrict__ coords0,
                                             const float* __restrict__ ws,
                                             float* __restrict__ out) {
    __shared__ float Gs[16 * 101];
    __shared__ float cxs[16], cys[16];
    const _Float16* wh = (const _Float16*)ws;

    const int t = threadIdx.x;
    const int w = t >> 6;               // wave = pixel-in-block
    const int ln = t & 63;
    const int oct = ln >> 3;            // dot within iteration
    const int sub = ln & 7;             // interleaved d slice

    const int gp0 = blockIdx.x * 16;
    const int gp = gp0 + w;

    int level, p;
    gp_to_level(gp, level, p);
    const int Hl = H0 >> level, Wl = W0 >> level;

    const int f1offs[4] = {H_F1T0, H_F1T1, H_F1T2, H_F1T3};
    const int f2offs[4] = {H_F2T0, H_F2T1, H_F2T2, H_F2T3};
    const int outoffs[4] = {OUT_L0, OUT_L1, OUT_L2, OUT_L3};

    const _Float16* f2t = wh + f2offs[level];

    // ---- coords for this wave's pixel
    float cx, cy;
    if (level == 0) {
        cx = coords0[p];
        cy = coords0[HW0 + p];
    } else {
        const int ho = p / Wl, wo = p - (p / Wl) * Wl;
        const float ff = (float)(1 << level);
        const float sfy = (ho + 0.5f) * ff - 0.5f;
        const float sfx = (wo + 0.5f) * ff - 0.5f;
        int ylo = max(0, (int)ceilf(sfy - ff));
        int yhi = min(H0 - 1, (int)floorf(sfy + ff));
        int xlo = max(0, (int)ceilf(sfx - ff));
        int xhi = min(W0 - 1, (int)floorf(sfx + ff));
        int nx = xhi - xlo + 1;
        int nt = (yhi - ylo + 1) * nx;
        float a0 = 0.0f, a1 = 0.0f, wsum = 0.0f;
        for (int i = ln; i < nt; i += 64) {
            int ry = i / nx, rx = i - ry * nx;
            int iy = ylo + ry, ix = xlo + rx;
            float wy = fmaxf(1.0f - fabsf(sfy - (float)iy) / ff, 0.0f);
            float wx = fmaxf(1.0f - fabsf(sfx - (float)ix) / ff, 0.0f);
            float wgt = wy * wx;
            wsum += wgt;
            a0 += wgt * coords0[iy * W0 + ix];
            a1 += wgt * coords0[HW0 + iy * W0 + ix];
        }
#pragma unroll
        for (int off = 32; off; off >>= 1) {
            a0 += __shfl_xor(a0, off);
            a1 += __shfl_xor(a1, off);
            wsum += __shfl_xor(wsum, off);
        }
        cx = a0 / wsum / ff;
        cy = a1 / wsum / ff;
    }
    if (ln == 0) { cxs[w] = cx; cys[w] = cy; }
    const int fx = (int)floorf(cx), fy = (int)floorf(cy);

    // ---- f1 fragment: d = j*64 + sub*8 + 0..7 (contiguous 128B across sub)
    const _Float16* f1p = wh + f1offs[level] + p * D + sub * 8;
    F4H a0f, a1f;
    a0f.f = *(const float4*)(f1p);
    a1f.f = *(const float4*)(f1p + 64);

    // ---- grid dots
#pragma unroll 2
    for (int i = 0; i < 13; ++i) {
        int g = i * 8 + oct;
        int gc = min(g, 99);
        int gy = gc / 10;
        int gx = gc - gy * 10;
        int iy = min(max(fy - 4 + gy, 0), Hl - 1);
        int ix = min(max(fx - 4 + gx, 0), Wl - 1);
        const _Float16* row = f2t + (iy * Wl + ix) * D + sub * 8;
        F4H v0, v1;
        v0.f = *(const float4*)(row);
        v1.f = *(const float4*)(row + 64);
        float s = 0.0f;
        s = dot2f(a0f.h[0], v0.h[0], s);
        s = dot2f(a0f.h[1], v0.h[1], s);
        s = dot2f(a0f.h[2], v0.h[2], s);
        s = dot2f(a0f.h[3], v0.h[3], s);
        s = dot2f(a1f.h[0], v1.h[0], s);
        s = dot2f(a1f.h[1], v1.h[1], s);
        s = dot2f(a1f.h[2], v1.h[2], s);
        s = dot2f(a1f.h[3], v1.h[3], s);
        s += __shfl_xor(s, 1);
        s += __shfl_xor(s, 2);
        s += __shfl_xor(s, 4);
        if (sub == 0 && g < 100) Gs[w * 101 + g] = s;
    }
    __syncthreads();

    // ---- combine: px = t&15, k-slot = t>>4 (block is level-uniform)
    {
        const int px = t & 15;
        const int kk = t >> 4;          // 0..63
        int lv0, p0;
        gp_to_level(gp0, lv0, p0);
        const int Hb = H0 >> lv0, Wb = W0 >> lv0;
        const int npb = Hb * Wb;
        float* outp = out + outoffs[lv0] + p0 + px;
        const float bx = cxs[px], by = cys[px];
        const float Wm1 = (float)(Wb - 1), Hm1 = (float)(Hb - 1);
        const float* Gp = &Gs[px * 101];

        for (int k = kk; k < 81; k += 64) {
            int dxi = k / 9, dyi = k - (k / 9) * 9;
            float x = fminf(fmaxf(bx + (float)(dxi - 4), 0.0f), Wm1);
            float y = fminf(fmaxf(by + (float)(dyi - 4), 0.0f), Hm1);
            float wx1 = x - floorf(x), wx0 = 1.0f - wx1;
            float wy1 = y - floorf(y), wy0 = 1.0f - wy1;
            int g00 = dyi * 10 + dxi;
            float v = wx0 * wy0 * Gp[g00]      + wx1 * wy0 * Gp[g00 + 1]
                    + wx0 * wy1 * Gp[g00 + 10] + wx1 * wy1 * Gp[g00 + 11];
            outp[k * npb] = v * INV_SQRT_D;
        }
    }
}

// ---------------------------------------------------------------------------
extern "C" void kernel_launch(void* const* d_in, const int* in_sizes, int n_in,
                              void* d_out, int out_size, void* d_ws, size_t ws_size,
                              hipStream_t stream) {
    const float* fmap1  = (const float*)d_in[0];
    const float* fmap2  = (const float*)d_in[1];
    const float* coords = (const float*)d_in[2];
    float* out = (float*)d_out;
    float* ws = (float*)d_ws;

    k_prep<<<dim3(384), dim3(256), 0, stream>>>(fmap1, fmap2, ws);
    k_dc<<<dim3(510), dim3(1024), 0, stream>>>(coords, ws, out);
}